// Round 2
// baseline (504.236 us; speedup 1.0000x reference)
//
#include <hip/hip_runtime.h>

#define HWS 65536           // H*W
#define NCH 60              // 40 upper + 20 lower output channels
#define NPIX (2 * HWS)      // B*H*W
#define INV_N (1.0f / 131072.0f)

// Pass 1: z[o] = sum_c xp[b,c,hw] * W[o,c];  y = att * z
// - store y into its FINAL d_out slot (parts 1..6)
// - accumulate per-channel sum / sumsq into stats[120] via block reduce + atomics
__global__ __launch_bounds__(256) void gnn_pass1(
    const float* __restrict__ xp,
    const float* __restrict__ h_att,
    const float* __restrict__ Wu,
    const float* __restrict__ Wl,
    float* __restrict__ out,
    float* __restrict__ stats)
{
    const int tid = threadIdx.x;
    const int pix = blockIdx.x * 256 + tid;   // 0 .. 131071
    const int b   = pix >> 16;
    const int hw  = pix & 65535;

    const float* xb = xp + (size_t)b * 256 * HWS + hw;
    // h_att shape (3,B,1,H,W): idx (i*2+b)*HWS + hw
    const float att1 = h_att[(size_t)(2 + b) * HWS + hw];
    const float att2 = h_att[(size_t)(4 + b) * HWS + hw];

    float acc[NCH];
#pragma unroll
    for (int o = 0; o < NCH; ++o) acc[o] = 0.0f;

#pragma unroll 4
    for (int c = 0; c < 256; ++c) {
        const float x = xb[(size_t)c * HWS];
#pragma unroll
        for (int o = 0; o < 40; ++o)
            acc[o] = fmaf(x, Wu[o * 256 + c], acc[o]);
#pragma unroll
        for (int o = 0; o < 20; ++o)
            acc[40 + o] = fmaf(x, Wl[o * 256 + c], acc[40 + o]);
    }

    __shared__ float red[4][2 * NCH];
    const int wave = tid >> 6;
    const int lane = tid & 63;

#pragma unroll
    for (int o = 0; o < NCH; ++o) {
        const float y = (o < 40 ? att1 : att2) * acc[o];
        // part index n = 1 + o/10, hid = o%10; out layout [7][B][10][HWS]
        const int n = 1 + o / 10;
        const size_t oidx = ((size_t)((n * 2 + b) * 10 + (o % 10))) * HWS + hw;
        out[oidx] = y;

        float s = y;
        float q = y * y;
#pragma unroll
        for (int m = 32; m >= 1; m >>= 1) {
            s += __shfl_xor(s, m, 64);
            q += __shfl_xor(q, m, 64);
        }
        if (lane == 0) {
            red[wave][2 * o]     = s;
            red[wave][2 * o + 1] = q;
        }
    }
    __syncthreads();
    if (tid < 2 * NCH) {
        const float v = red[0][tid] + red[1][tid] + red[2][tid] + red[3][tid];
        atomicAdd(&stats[tid], v);
    }
}

// Pass 2: finalize BN per channel, ReLU, blend with p_nodes (parts 1..6);
// part 0 = 0.5*(h_nodes[0] + p_nodes[0]).  float4 over out.
__global__ __launch_bounds__(256) void gnn_pass2(
    const float* __restrict__ p_nodes,
    const float* __restrict__ h_nodes,
    const float* __restrict__ gamma_u, const float* __restrict__ beta_u,
    const float* __restrict__ gamma_l, const float* __restrict__ beta_l,
    const float* __restrict__ stats,
    float* __restrict__ out)
{
    const size_t g = (size_t)blockIdx.x * 256 + threadIdx.x;
    const size_t base = g * 4;                 // 4 | HWS so one slice per vec
    const int slice = (int)(base >> 16);       // ((n*2+b)*10+hid), 0..139
    const int n  = slice / 20;
    const int bh = slice % 20;

    const float4 pv = *reinterpret_cast<const float4*>(p_nodes + base);
    float4 r;
    if (n == 0) {
        // h_nodes[0][b][hid][hw] has the same flat index as base
        const float4 hv = *reinterpret_cast<const float4*>(h_nodes + base);
        r.x = 0.5f * (hv.x + pv.x);
        r.y = 0.5f * (hv.y + pv.y);
        r.z = 0.5f * (hv.z + pv.z);
        r.w = 0.5f * (hv.w + pv.w);
    } else {
        const int hid = bh % 10;
        const int o = (n - 1) * 10 + hid;      // 0..59
        const float mean = stats[2 * o] * INV_N;
        const float var  = stats[2 * o + 1] * INV_N - mean * mean;
        const float rstd = rsqrtf(var + 1e-5f);
        const float gm = (o < 40) ? gamma_u[o] : gamma_l[o - 40];
        const float bt = (o < 40) ? beta_u[o]  : beta_l[o - 40];
        const float a  = rstd * gm;
        const float c0 = bt - mean * a;
        const float4 y = *reinterpret_cast<const float4*>(out + base);
        r.x = 0.5f * (pv.x + fmaxf(fmaf(y.x, a, c0), 0.0f));
        r.y = 0.5f * (pv.y + fmaxf(fmaf(y.y, a, c0), 0.0f));
        r.z = 0.5f * (pv.z + fmaxf(fmaf(y.z, a, c0), 0.0f));
        r.w = 0.5f * (pv.w + fmaxf(fmaf(y.w, a, c0), 0.0f));
    }
    *reinterpret_cast<float4*>(out + base) = r;
}

extern "C" void kernel_launch(void* const* d_in, const int* in_sizes, int n_in,
                              void* d_out, int out_size, void* d_ws, size_t ws_size,
                              hipStream_t stream) {
    const float* p_nodes = (const float*)d_in[0];
    const float* h_nodes = (const float*)d_in[1];
    // d_in[2] = f_nodes (unused by reference)
    const float* xp      = (const float*)d_in[3];
    const float* h_att   = (const float*)d_in[4];
    const float* Wu      = (const float*)d_in[5];
    const float* Wl      = (const float*)d_in[6];
    const float* gu      = (const float*)d_in[7];
    const float* bu      = (const float*)d_in[8];
    const float* gl      = (const float*)d_in[9];
    const float* bl      = (const float*)d_in[10];
    float* out   = (float*)d_out;
    float* stats = (float*)d_ws;               // 120 floats

    hipMemsetAsync(stats, 0, 2 * NCH * sizeof(float), stream);
    gnn_pass1<<<NPIX / 256, 256, 0, stream>>>(xp, h_att, Wu, Wl, out, stats);
    // total out elems = 7*2*10*65536 = 9,175,040 ; /4 /256 = 8960 blocks
    gnn_pass2<<<8960, 256, 0, stream>>>(p_nodes, h_nodes, gu, bu, gl, bl, stats, out);
}

// Round 4
// 323.268 us; speedup vs baseline: 1.5598x; 1.5598x over previous
//
#include <hip/hip_runtime.h>

#define HWS 65536           // H*W
#define NCH 60
#define INV_N (1.0f / 131072.0f)

typedef short bf16x8 __attribute__((ext_vector_type(8)));
typedef float f32x4  __attribute__((ext_vector_type(4)));

__device__ __forceinline__ unsigned short f2bf(float x) {
    unsigned u = __float_as_uint(x);
    return (unsigned short)((u + 0x7FFFu + ((u >> 16) & 1u)) >> 16);  // RNE
}

// Pass 1 (MFMA): per wave, 64ch x 16px tile. A = W (64x256, rows>=60 clamped),
// B = x (256 x 16px) gathered per-lane from global (4x64B segments/inst).
// y = att * (W @ x) stored to final out slot; per-channel sum/sumsq -> stats.
__global__ __launch_bounds__(256) void gnn_pass1(
    const float* __restrict__ xp,
    const float* __restrict__ h_att,
    const float* __restrict__ Wu,
    const float* __restrict__ Wl,
    float* __restrict__ out,
    float* __restrict__ stats)
{
    const int tid  = threadIdx.x;
    const int lane = tid & 63;
    const int wid  = tid >> 6;
    const int rr   = lane & 15;    // px offset within tile / A row-in-tile
    const int g    = lane >> 4;    // k-slot group (0..3)

    // per-lane W row pointers for the 4 ch-tiles (ch = 16t + rr, clamp >=60)
    const float* wrow[4];
#pragma unroll
    for (int t = 0; t < 4; ++t) {
        int row = 16 * t + rr;
        int rc  = row < 59 ? row : 59;
        wrow[t] = (rc < 40) ? (Wu + rc * 256) : (Wl + (rc - 40) * 256);
    }

    __shared__ float red[4][128];         // [wave][2*ch] sum/sq interleaved
    ((float*)red)[tid]       = 0.0f;
    ((float*)red)[tid + 256] = 0.0f;
    __syncthreads();

#pragma unroll 2
    for (int it = 0; it < 2; ++it) {
        const int px = blockIdx.x * 128 + it * 64 + wid * 16 + rr;  // 0..131071
        const int b  = px >> 16;
        const int hw = px & 65535;

        const float* xb = xp + (size_t)b * 256 * HWS + hw;
        const float att1 = h_att[(size_t)(2 + b) * HWS + hw];
        const float att2 = h_att[(size_t)(4 + b) * HWS + hw];

        f32x4 acc[4];
#pragma unroll
        for (int t = 0; t < 4; ++t) acc[t] = (f32x4){0.f, 0.f, 0.f, 0.f};

#pragma unroll 2
        for (int s = 0; s < 8; ++s) {
            const int k0 = 32 * s + 8 * g;
            // B fragment: x[k0..k0+7][px]
            float xv[8];
#pragma unroll
            for (int j = 0; j < 8; ++j)
                xv[j] = xb[(size_t)(k0 + j) * HWS];
            bf16x8 bfr;
#pragma unroll
            for (int j = 0; j < 8; ++j) bfr[j] = (short)f2bf(xv[j]);

#pragma unroll
            for (int t = 0; t < 4; ++t) {
                const float4 wa = *reinterpret_cast<const float4*>(wrow[t] + k0);
                const float4 wb = *reinterpret_cast<const float4*>(wrow[t] + k0 + 4);
                bf16x8 afr;
                afr[0] = (short)f2bf(wa.x); afr[1] = (short)f2bf(wa.y);
                afr[2] = (short)f2bf(wa.z); afr[3] = (short)f2bf(wa.w);
                afr[4] = (short)f2bf(wb.x); afr[5] = (short)f2bf(wb.y);
                afr[6] = (short)f2bf(wb.z); afr[7] = (short)f2bf(wb.w);
                acc[t] = __builtin_amdgcn_mfma_f32_16x16x32_bf16(afr, bfr, acc[t], 0, 0, 0);
            }
        }

        // epilogue: scale by att, store, per-channel partial stats
#pragma unroll
        for (int t = 0; t < 4; ++t) {
#pragma unroll
            for (int r = 0; r < 4; ++r) {
                const int o = 16 * t + 4 * g + r;       // channel (per-lane, via g)
                float y = (o < 40 ? att1 : att2) * acc[t][r];
                if (o >= 60) y = 0.0f;                  // padded channels
                if (o < 60) {
                    const int n   = 1 + o / 10;
                    const int hid = o % 10;
                    out[((size_t)((n * 2 + b) * 10 + hid)) * HWS + hw] = y;
                }
                float s = y, q = y * y;
#pragma unroll
                for (int m = 1; m <= 8; m <<= 1) {
                    s += __shfl_xor(s, m, 64);
                    q += __shfl_xor(q, m, 64);
                }
                if (rr == 0) {
                    red[wid][2 * o]     += s;
                    red[wid][2 * o + 1] += q;
                }
            }
        }
    }

    __syncthreads();
    if (tid < 2 * NCH) {
        const float v = red[0][tid] + red[1][tid] + red[2][tid] + red[3][tid];
        atomicAdd(&stats[tid], v);
    }
}

// Pass 2: finalize BN per channel, ReLU, blend with p_nodes (parts 1..6);
// part 0 = 0.5*(h_nodes[0] + p_nodes[0]).  float4 over out.
__global__ __launch_bounds__(256) void gnn_pass2(
    const float* __restrict__ p_nodes,
    const float* __restrict__ h_nodes,
    const float* __restrict__ gamma_u, const float* __restrict__ beta_u,
    const float* __restrict__ gamma_l, const float* __restrict__ beta_l,
    const float* __restrict__ stats,
    float* __restrict__ out)
{
    const size_t g = (size_t)blockIdx.x * 256 + threadIdx.x;
    const size_t base = g * 4;
    const int slice = (int)(base >> 16);       // ((n*2+b)*10+hid), 0..139
    const int n  = slice / 20;
    const int bh = slice % 20;

    const float4 pv = *reinterpret_cast<const float4*>(p_nodes + base);
    float4 r;
    if (n == 0) {
        const float4 hv = *reinterpret_cast<const float4*>(h_nodes + base);
        r.x = 0.5f * (hv.x + pv.x);
        r.y = 0.5f * (hv.y + pv.y);
        r.z = 0.5f * (hv.z + pv.z);
        r.w = 0.5f * (hv.w + pv.w);
    } else {
        const int hid = bh % 10;
        const int o = (n - 1) * 10 + hid;      // 0..59
        const float mean = stats[2 * o] * INV_N;
        const float var  = stats[2 * o + 1] * INV_N - mean * mean;
        const float rstd = rsqrtf(var + 1e-5f);
        const float gm = (o < 40) ? gamma_u[o] : gamma_l[o - 40];
        const float bt = (o < 40) ? beta_u[o]  : beta_l[o - 40];
        const float a  = rstd * gm;
        const float c0 = bt - mean * a;
        const float4 y = *reinterpret_cast<const float4*>(out + base);
        r.x = 0.5f * (pv.x + fmaxf(fmaf(y.x, a, c0), 0.0f));
        r.y = 0.5f * (pv.y + fmaxf(fmaf(y.y, a, c0), 0.0f));
        r.z = 0.5f * (pv.z + fmaxf(fmaf(y.z, a, c0), 0.0f));
        r.w = 0.5f * (pv.w + fmaxf(fmaf(y.w, a, c0), 0.0f));
    }
    *reinterpret_cast<float4*>(out + base) = r;
}

extern "C" void kernel_launch(void* const* d_in, const int* in_sizes, int n_in,
                              void* d_out, int out_size, void* d_ws, size_t ws_size,
                              hipStream_t stream) {
    const float* p_nodes = (const float*)d_in[0];
    const float* h_nodes = (const float*)d_in[1];
    // d_in[2] = f_nodes (unused by reference)
    const float* xp      = (const float*)d_in[3];
    const float* h_att   = (const float*)d_in[4];
    const float* Wu      = (const float*)d_in[5];
    const float* Wl      = (const float*)d_in[6];
    const float* gu      = (const float*)d_in[7];
    const float* bu      = (const float*)d_in[8];
    const float* gl      = (const float*)d_in[9];
    const float* bl      = (const float*)d_in[10];
    float* out   = (float*)d_out;
    float* stats = (float*)d_ws;               // 120 floats

    hipMemsetAsync(stats, 0, 2 * NCH * sizeof(float), stream);
    // pass1: 1024 blocks x 256 thr; each block covers 128 px (2 tiles of 64)
    gnn_pass1<<<1024, 256, 0, stream>>>(xp, h_att, Wu, Wl, out, stats);
    gnn_pass2<<<8960, 256, 0, stream>>>(p_nodes, h_nodes, gu, bu, gl, bl, stats, out);
}